// Round 8
// baseline (1470.517 us; speedup 1.0000x reference)
//
#include <hip/hip_runtime.h>
#include <hip/hip_bf16.h>
#include <math.h>

// Problem constants
#define BB 4
#define CIN 64
#define DI 128       // D_INNER
#define NS 16        // D_STATE
#define HH 256
#define WW 256
#define HW 65536     // HH*WW (2^16)
#define NCH_P 33     // 1 + 2*NS

// ---------------------------------------------------------------- fast math helpers
__device__ __forceinline__ float softplusf(float x) {
    return fmaxf(x, 0.f) + __logf(1.0f + __expf(-fabsf(x)));
}
__device__ __forceinline__ float tanh_half(float a) {   // tanh(0.5*a)
    return 1.0f - 2.0f / (1.0f + __expf(a));
}
__device__ __forceinline__ float sigmoidf(float z) {
    return 1.0f / (1.0f + __expf(-z));
}

__device__ __forceinline__ void gauss15(float* g) {
    float s = 0.f;
#pragma unroll
    for (int i = 0; i < 15; ++i) {
        float a = (float)i - 7.0f;
        g[i] = __expf(-a * a / 18.0f);   // 2*sigma^2 = 18
        s += g[i];
    }
    float inv = 1.0f / s;
#pragma unroll
    for (int i = 0; i < 15; ++i) g[i] *= inv;
}

// ---------------------------------------------------------------- K1: in_proj, one batch
// y-group 0,1: U rows (o 0..127), original arithmetic (a0 starts at bias).
// y-group 2,3: Z rows (o 128..255): z accumulated from 0, bias added at END,
// then sigmoid — replicates k_gate's exact order -> bit-exact gate later.
// Launch with gridDim.y = 2 (U only, fallback paths) or 4 (U + sigZ).
__global__ __launch_bounds__(256) void k_inproj4(
    const float* __restrict__ xb, const float* __restrict__ w,
    const float* __restrict__ bias, float* __restrict__ Ub,
    float* __restrict__ Zb) {
    int p = blockIdx.x * 256 + threadIdx.x;
    int og = blockIdx.y * 64;
    float xv[CIN];
#pragma unroll
    for (int c = 0; c < CIN; ++c) xv[c] = xb[(size_t)c * HW + p];
    if (og < DI) {
#pragma unroll 2
        for (int o = og; o < og + 64; ++o) {
            float a0 = bias[o], a1 = 0.f, a2 = 0.f, a3 = 0.f;
            const float* wr = w + o * CIN;
#pragma unroll
            for (int c = 0; c < CIN; c += 4) {
                a0 = fmaf(xv[c],     wr[c],     a0);
                a1 = fmaf(xv[c + 1], wr[c + 1], a1);
                a2 = fmaf(xv[c + 2], wr[c + 2], a2);
                a3 = fmaf(xv[c + 3], wr[c + 3], a3);
            }
            Ub[(size_t)o * HW + p] = (a0 + a1) + (a2 + a3);
        }
    } else {
#pragma unroll 2
        for (int o = og; o < og + 64; ++o) {
            float z0 = 0.f, z1 = 0.f, z2 = 0.f, z3 = 0.f;
            const float* wr = w + o * CIN;          // == wz + (o-DI)*CIN
#pragma unroll
            for (int c = 0; c < CIN; c += 4) {
                z0 = fmaf(xv[c],     wr[c],     z0);
                z1 = fmaf(xv[c + 1], wr[c + 1], z1);
                z2 = fmaf(xv[c + 2], wr[c + 2], z2);
                z3 = fmaf(xv[c + 3], wr[c + 3], z3);
            }
            float z = bias[o] + ((z0 + z1) + (z2 + z3));   // bias[o] == bz[o-DI]
            Zb[(size_t)(o - DI) * HW + p] = sigmoidf(z);
        }
    }
}

// ---------------------------------------------------------------- K2: fused dw3x3+tanh+15x15 highpass, one batch
#define TILE_H 16
__global__ __launch_bounds__(256) void k_conv(
    const float* __restrict__ Ub, const float* __restrict__ dww,
    const float* __restrict__ dwb, float* __restrict__ Ucb) {
    __shared__ float sU[32 * 256];
    __shared__ float sC[30 * 272];
    int c  = blockIdx.x >> 4;
    int t  = blockIdx.x & 15;
    int h0 = t * TILE_H;
    int w  = threadIdx.x;

    const float* base = Ub + (size_t)c * HW;
#pragma unroll
    for (int i = 0; i < 32; ++i) {
        int hh = h0 + i - 8;
        sU[i * 256 + w] = (hh >= 0 && hh < HH) ? base[hh * WW + w] : 0.f;
    }
    __syncthreads();

    float wt[9];
#pragma unroll
    for (int i = 0; i < 9; ++i) wt[i] = dww[c * 9 + i];
    float bb = dwb[c];

#pragma unroll
    for (int i = 0; i < 30; ++i) {
        int r = h0 + i - 7;
        float v = 0.f;
        if (r >= 0 && r < HH) {
            float acc = bb;
#pragma unroll
            for (int ky = 0; ky < 3; ++ky) {
                const float* ur = sU + (i + ky) * 256;
#pragma unroll
                for (int kx = 0; kx < 3; ++kx) {
                    int ww = w + kx - 1;
                    if (ww >= 0 && ww < WW) acc = fmaf(ur[ww], wt[ky * 3 + kx], acc);
                }
            }
            v = tanh_half(acc);
        }
        sC[i * 272 + w + 7] = v;
    }
    if (w < 7) {
#pragma unroll
        for (int i = 0; i < 30; ++i) { sC[i * 272 + w] = 0.f; sC[i * 272 + w + 263] = 0.f; }
    }
    __syncthreads();

    float g[15]; gauss15(g);
#pragma unroll
    for (int i = 0; i < 30; ++i) {
        float acc = 0.f;
#pragma unroll
        for (int k = 0; k < 15; ++k) acc = fmaf(sC[i * 272 + w + k], g[k], acc);
        sU[i * 256 + w] = acc;
    }
    float* outp = Ucb + (size_t)c * HW + h0 * WW + w;
#pragma unroll
    for (int i = 0; i < TILE_H; ++i) {
        float acc = 0.f;
#pragma unroll
        for (int k = 0; k < 15; ++k) acc = fmaf(sU[(i + k) * 256 + w], g[k], acc);
        float center = sC[(i + 7) * 272 + w + 7];
        outp[i * WW] = center - acc;
    }
}

// ---------------------------------------------------------------- K5: x_proj (128 -> 33), nb batches
__global__ __launch_bounds__(256) void k_xproj(
    const float* __restrict__ Uc, const float* __restrict__ xw,
    float* __restrict__ P) {
    int p = blockIdx.x * 256 + threadIdx.x;
    int b = p >> 16;
    int rem = p & 65535;
    const float* up = Uc + (size_t)b * DI * HW + rem;
    float acc[NCH_P];
#pragma unroll
    for (int o = 0; o < NCH_P; ++o) acc[o] = 0.f;
    for (int c = 0; c < DI; ++c) {
        float u = up[(size_t)c * HW];
#pragma unroll
        for (int o = 0; o < NCH_P; ++o) acc[o] = fmaf(u, xw[o * DI + c], acc[o]);
    }
    float* pp = P + (size_t)b * NCH_P * HW + rem;
#pragma unroll
    for (int o = 0; o < NCH_P; ++o) pp[(size_t)o * HW] = acc[o];
}

// ---------------------------------------------------------------- K6: scan along W, LDS-staged u AND P, reg-prefetch
#define CW 32
__global__ __launch_bounds__(128) void k_scan_w(
    float* __restrict__ UY, const float* __restrict__ P,
    const float* __restrict__ A_log, const float* __restrict__ dtw,
    const float* __restrict__ dtb, const float* __restrict__ Dv) {
    __shared__ float sU[DI * 33];
    __shared__ float sP[CW * 36];
    int bh = blockIdx.x;
    int b = bh >> 8;
    int h = bh & 255;
    int t = threadIdx.x;                   // d

    float Av[NS];
#pragma unroll
    for (int n = 0; n < NS; ++n) Av[n] = -__expf(A_log[t * NS + n]);
    float wdt = dtw[t], bdt = dtb[t], Dd = Dv[t];
    float hS[NS];
#pragma unroll
    for (int n = 0; n < NS; ++n) hS[n] = 0.f;

    float* ubase = UY + (size_t)(b * DI) * HW + (size_t)h * WW;
    const float* prow = P + (size_t)(b * NCH_P) * HW + (size_t)h * WW;

    const int w4 = (t & 7) * 4;
    const int dbase = t >> 3;

    float4 rU[8];
    float rP[9];
#pragma unroll
    for (int p = 0; p < 8; ++p)
        rU[p] = *(const float4*)(ubase + (size_t)(dbase + p * 16) * HW + w4);
#pragma unroll
    for (int i = 0; i < 9; ++i) {
        int idx = i * 128 + t, ch = idx >> 5, wi = idx & 31;
        rP[i] = (ch < NCH_P) ? prow[(size_t)ch * HW + wi] : 0.f;
    }

    for (int w0 = 0; w0 < WW; w0 += CW) {
#pragma unroll
        for (int p = 0; p < 8; ++p) {
            float* s = sU + (dbase + p * 16) * 33 + w4;
            s[0] = rU[p].x; s[1] = rU[p].y; s[2] = rU[p].z; s[3] = rU[p].w;
        }
#pragma unroll
        for (int i = 0; i < 9; ++i) {
            int idx = i * 128 + t, ch = idx >> 5, wi = idx & 31;
            if (ch < NCH_P) sP[wi * 36 + ch] = rP[i];
        }
        __syncthreads();
        if (w0 + CW < WW) {
#pragma unroll
            for (int p = 0; p < 8; ++p)
                rU[p] = *(const float4*)(ubase + (size_t)(dbase + p * 16) * HW + w0 + CW + w4);
#pragma unroll
            for (int i = 0; i < 9; ++i) {
                int idx = i * 128 + t, ch = idx >> 5, wi = idx & 31;
                rP[i] = (ch < NCH_P) ? prow[(size_t)ch * HW + w0 + CW + wi] : 0.f;
            }
        }
#pragma unroll 2
        for (int wi = 0; wi < CW; ++wi) {
            const float* pr = sP + wi * 36;
            float4 q0 = *(const float4*)(pr);
            float4 q1 = *(const float4*)(pr + 4);
            float4 q2 = *(const float4*)(pr + 8);
            float4 q3 = *(const float4*)(pr + 12);
            float4 q4 = *(const float4*)(pr + 16);
            float4 q5 = *(const float4*)(pr + 20);
            float4 q6 = *(const float4*)(pr + 24);
            float4 q7 = *(const float4*)(pr + 28);
            float q8 = pr[32];
            float u = sU[t * 33 + wi];
            float dt = softplusf(fmaf(q0.x, wdt, bdt));
            float ud = u * dt;
            float y = Dd * u;
            float Bv[NS] = {q0.y,q0.z,q0.w,q1.x,q1.y,q1.z,q1.w,q2.x,
                            q2.y,q2.z,q2.w,q3.x,q3.y,q3.z,q3.w,q4.x};
            float Cv[NS] = {q4.y,q4.z,q4.w,q5.x,q5.y,q5.z,q5.w,q6.x,
                            q6.y,q6.z,q6.w,q7.x,q7.y,q7.z,q7.w,q8};
#pragma unroll
            for (int n = 0; n < NS; ++n) {
                float e = __expf(dt * Av[n]);
                hS[n] = fmaf(e, hS[n], ud * Bv[n]);
                y = fmaf(hS[n], Cv[n], y);
            }
            sU[t * 33 + wi] = y;
        }
        __syncthreads();
#pragma unroll
        for (int p = 0; p < 8; ++p) {
            const float* s = sU + (dbase + p * 16) * 33 + w4;
            float4 v; v.x = s[0]; v.y = s[1]; v.z = s[2]; v.w = s[3];
            *(float4*)(ubase + (size_t)(dbase + p * 16) * HW + w0 + w4) = v;
        }
        __syncthreads();
    }
}

// ---------------------------------------------------------------- K7 v3: scan along H, P shared across d-group, 4-row dbuf
// R7 structure (4d x 64w blocks, LDS-shared P) with 4-row double buffers:
// barriers per 8 rows = 2 (was 4), 18 global loads issued per LD (better MLP).
// u prefetched 8 rows ahead (8 slots). Live ~90 floats; spill tripwire:
// WRITE_SIZE must stay exactly 131072 KB.
#define WT2 64

#define LD4(hb) { \
    _Pragma("unroll") for (int rr = 0; rr < 4; ++rr) { \
        int hp = (hb) + rr; if (hp > HH - 1) hp = HH - 1; \
        const float* pr_ = pt + hp * WW; \
        _Pragma("unroll") for (int k = 0; k < 8; ++k) rp[rr][k] = pr_[(size_t)(4 * k) * HW]; \
        rp8[rr] = (dl == 0) ? pr_[(size_t)32 * HW] : 0.f; \
    } }
#define WR4(bf) { \
    _Pragma("unroll") for (int rr = 0; rr < 4; ++rr) { \
        _Pragma("unroll") for (int k = 0; k < 8; ++k) sP[bf][rr][4 * k + dl][wl] = rp[rr][k]; \
        if (dl == 0) sP[bf][rr][32][wl] = rp8[rr]; \
    } }
#define PU4(uu, hp_) { int hp = (hp_); if (hp > HH - 1) hp = HH - 1; uu = ub[hp * WW]; }
#define CP4(bf, rr, hh, uu) { \
    const float* pr_ = &sP[bf][rr][0][wl]; \
    float de = pr_[0]; \
    float dt = softplusf(fmaf(de, wdt, bdt)); \
    float ud = (uu) * dt; \
    float y = Dd * (uu); \
    _Pragma("unroll") for (int n = 0; n < NS; ++n) { \
        float e = __expf(dt * Av[n]); \
        hS[n] = fmaf(e, hS[n], ud * pr_[(1 + n) * WT2]); \
        y = fmaf(hS[n], pr_[(17 + n) * WT2], y); } \
    ub[(hh) * WW] = y; }

__global__ __launch_bounds__(256) void k_scan_h(
    float* __restrict__ UY, const float* __restrict__ P,
    const float* __restrict__ A_log, const float* __restrict__ dtw,
    const float* __restrict__ dtb, const float* __restrict__ Dv) {
    __shared__ float sP[2][4][NCH_P][WT2];   // 67,584 B -> 2 blocks/CU
    int bid = blockIdx.x;
    int b  = bid >> 7;          // 128 blocks per batch
    int r  = bid & 127;
    int wt = r >> 5;            // w-tile 0..3
    int dg = r & 31;            // d-group 0..31
    int t  = threadIdx.x;
    int dl = t >> 6;            // 0..3 (wave-uniform)
    int wl = t & 63;
    int d  = dg * 4 + dl;

    float Av[NS];
#pragma unroll
    for (int n = 0; n < NS; ++n) Av[n] = -__expf(A_log[d * NS + n]);
    float wdt = dtw[d], bdt = dtb[d], Dd = Dv[d];
    float hS[NS];
#pragma unroll
    for (int n = 0; n < NS; ++n) hS[n] = 0.f;

    float* ub = UY + (size_t)(b * DI + d) * HW + wt * WT2 + wl;
    const float* pt = P + (size_t)b * NCH_P * HW + (size_t)dl * HW + wt * WT2 + wl;

    float rp[4][8], rp8[4];
    float u0, u1, u2, u3, u4, u5, u6, u7;

    // prologue: rows 0..3 staged in buf0; rp <- rows 4..7; u for rows 0..7
    LD4(0);
    PU4(u0, 0); PU4(u1, 1); PU4(u2, 2); PU4(u3, 3);
    PU4(u4, 4); PU4(u5, 5); PU4(u6, 6); PU4(u7, 7);
    WR4(0);
    __syncthreads();
    LD4(4);

#pragma unroll 1
    for (int h0 = 0; h0 < HH; h0 += 8) {
        // buf0 = rows h0..h0+3; rp = rows h0+4..h0+7
        CP4(0, 0, h0,     u0);
        CP4(0, 1, h0 + 1, u1);
        CP4(0, 2, h0 + 2, u2);
        CP4(0, 3, h0 + 3, u3);
        WR4(1);
        __syncthreads();
        LD4(h0 + 8);
        PU4(u0, h0 + 8);  PU4(u1, h0 + 9);
        PU4(u2, h0 + 10); PU4(u3, h0 + 11);
        // buf1 = rows h0+4..h0+7; rp = rows h0+8..h0+11
        CP4(1, 0, h0 + 4, u4);
        CP4(1, 1, h0 + 5, u5);
        CP4(1, 2, h0 + 6, u6);
        CP4(1, 3, h0 + 7, u7);
        WR4(0);
        __syncthreads();
        LD4(h0 + 12);
        PU4(u4, h0 + 12); PU4(u5, h0 + 13);
        PU4(u6, h0 + 14); PU4(u7, h0 + 15);
    }
}

// ---------------------------------------------------------------- K8a/K8b: fallback back end (proven R2/R7 versions)
__global__ __launch_bounds__(256) void k_gate(
    float* __restrict__ Y, const float* __restrict__ x,
    const float* __restrict__ wz, const float* __restrict__ bz) {
    int p = blockIdx.x * 256 + threadIdx.x;
    int b = p >> 16;
    int rem = p & 65535;
    const float* xp = x + (size_t)b * CIN * HW + rem;
    float xv[CIN];
#pragma unroll
    for (int c = 0; c < CIN; ++c) xv[c] = xp[(size_t)c * HW];
    float* yp = Y + (size_t)b * DI * HW + rem;
#pragma unroll 2
    for (int dd = 0; dd < DI; ++dd) {
        float z0 = 0.f, z1 = 0.f, z2 = 0.f, z3 = 0.f;
        const float* wr = wz + dd * CIN;
#pragma unroll
        for (int c = 0; c < CIN; c += 4) {
            z0 = fmaf(xv[c],     wr[c],     z0);
            z1 = fmaf(xv[c + 1], wr[c + 1], z1);
            z2 = fmaf(xv[c + 2], wr[c + 2], z2);
            z3 = fmaf(xv[c + 3], wr[c + 3], z3);
        }
        float z = bz[dd] + ((z0 + z1) + (z2 + z3));
        float yv = yp[(size_t)dd * HW];
        yp[(size_t)dd * HW] = yv * sigmoidf(z);
    }
}

__global__ __launch_bounds__(256) void k_out2(
    const float* __restrict__ G, const float* __restrict__ ow,
    const float* __restrict__ ob, float* __restrict__ outp) {
    int p = blockIdx.x * 256 + threadIdx.x;
    int b = p >> 16;
    int rem = p & 65535;
    const float* gp = G + (size_t)b * DI * HW + rem;
    float acc[CIN];
#pragma unroll
    for (int c = 0; c < CIN; ++c) acc[c] = 0.f;
    for (int dd = 0; dd < DI; ++dd) {
        float g = gp[(size_t)dd * HW];
#pragma unroll
        for (int c = 0; c < CIN; ++c) acc[c] = fmaf(g, ow[c * DI + dd], acc[c]);
    }
    float* op = outp + (size_t)b * CIN * HW + rem;
#pragma unroll
    for (int c = 0; c < CIN; ++c) op[(size_t)c * HW] = acc[c] + ob[c];
}

// ---------------------------------------------------------------- K8 v3: tiled out-projection with fused gate
// out[c][px] = ob[c] + sum_{k=0..127} ow[c][k] * (Y[k][px] * sigZ[k][px])
// Block: 64-px tile x all 64 c. ow staged in LDS (stride 129: conflict-free);
// G = Y*sigZ staged per 32-k chunk. Thread owns 4c x 4px acc. k strictly
// ascending -> accumulation order identical to k_gate+k_out2 -> bit-exact.
__global__ __launch_bounds__(256) void k_out2g(
    const float* __restrict__ Y, const float* __restrict__ Z,
    const float* __restrict__ ow, const float* __restrict__ ob,
    float* __restrict__ outp) {
    __shared__ float sOw[64 * 129];        // 33,024 B
    __shared__ float sG[32 * 64];          // 8,192 B
    int t = threadIdx.x;
    int bid = blockIdx.x;
    int b   = bid >> 10;
    int pxb = (bid & 1023) << 6;

    // stage ow once (coalesced)
#pragma unroll
    for (int i = 0; i < 32; ++i) {
        int idx = i * 256 + t;
        int c = idx >> 7, k = idx & 127;
        sOw[c * 129 + k] = ow[c * DI + k];
    }

    const int c0  = (t >> 4) * 4;
    const int px0 = (t & 15) * 4;
    const int ks  = t >> 3;                // stage row 0..31
    const int pq  = (t & 7) * 8;           // stage px offset

    float4 acc[4];
#pragma unroll
    for (int i = 0; i < 4; ++i) acc[i] = make_float4(0.f, 0.f, 0.f, 0.f);

    for (int kk0 = 0; kk0 < DI; kk0 += 32) {
        __syncthreads();                   // sG free (and sOw ready on first pass)
        const float* yr = Y + (size_t)(b * DI + kk0 + ks) * HW + pxb + pq;
        const float* zr = Z + (size_t)(b * DI + kk0 + ks) * HW + pxb + pq;
        float4 ya = *(const float4*)(yr);
        float4 yb = *(const float4*)(yr + 4);
        float4 za = *(const float4*)(zr);
        float4 zb = *(const float4*)(zr + 4);
        float4 ga, gb;
        ga.x = ya.x * za.x; ga.y = ya.y * za.y; ga.z = ya.z * za.z; ga.w = ya.w * za.w;
        gb.x = yb.x * zb.x; gb.y = yb.y * zb.y; gb.z = yb.z * zb.z; gb.w = yb.w * zb.w;
        *(float4*)&sG[ks * 64 + pq]     = ga;
        *(float4*)&sG[ks * 64 + pq + 4] = gb;
        __syncthreads();
#pragma unroll
        for (int k = 0; k < 32; ++k) {
            float4 g = *(const float4*)&sG[k * 64 + px0];
#pragma unroll
            for (int ci = 0; ci < 4; ++ci) {
                float wv = sOw[(c0 + ci) * 129 + kk0 + k];
                acc[ci].x = fmaf(g.x, wv, acc[ci].x);
                acc[ci].y = fmaf(g.y, wv, acc[ci].y);
                acc[ci].z = fmaf(g.z, wv, acc[ci].z);
                acc[ci].w = fmaf(g.w, wv, acc[ci].w);
            }
        }
    }
#pragma unroll
    for (int ci = 0; ci < 4; ++ci) {
        float o = ob[c0 + ci];
        float4 r = acc[ci];
        r.x += o; r.y += o; r.z += o; r.w += o;
        *(float4*)(outp + (size_t)(b * CIN + c0 + ci) * HW + pxb + px0) = r;
    }
}

// ---------------------------------------------------------------- launch
extern "C" void kernel_launch(void* const* d_in, const int* in_sizes, int n_in,
                              void* d_out, int out_size, void* d_ws, size_t ws_size,
                              hipStream_t stream) {
    const float* x     = (const float*)d_in[0];
    const float* ipw   = (const float*)d_in[1];
    const float* ipb   = (const float*)d_in[2];
    const float* dww   = (const float*)d_in[3];
    const float* dwb   = (const float*)d_in[4];
    const float* xpw   = (const float*)d_in[5];
    const float* dtw   = (const float*)d_in[6];
    const float* dtb   = (const float*)d_in[7];
    const float* A_log = (const float*)d_in[8];
    const float* Dv    = (const float*)d_in[9];
    const float* ow    = (const float*)d_in[10];
    const float* ob    = (const float*)d_in[11];
    float* out = (float*)d_out;

    const float* wz = ipw + (size_t)DI * CIN;
    const float* bz = ipb + DI;

    const size_t PLANE = (size_t)DI * HW;
    const size_t NB    = (size_t)BB * PLANE;

    if (ws_size >= (2 * NB + PLANE) * sizeof(float)) {
        // ---------- Path A+: ws = Y(4 planes) + Z(4 planes) + U(1); P in d_out.
        float* bufY = (float*)d_ws;
        float* bufZ = bufY + NB;
        float* bufU = bufZ + NB;
        float* P    = out;
        for (int b = 0; b < BB; ++b) {
            k_inproj4<<<dim3(HW / 256, 4), 256, 0, stream>>>(
                x + (size_t)b * CIN * HW, ipw, ipb, bufU, bufZ + (size_t)b * PLANE);
            k_conv<<<DI * 16, 256, 0, stream>>>(bufU, dww, dwb, bufY + (size_t)b * PLANE);
        }
        k_xproj<<<BB * (HW / 256), 256, 0, stream>>>(bufY, xpw, P);
        k_scan_w<<<BB * HH, 128, 0, stream>>>(bufY, P, A_log, dtw, dtb, Dv);
        k_scan_h<<<BB * 128, 256, 0, stream>>>(bufY, P, A_log, dtw, dtb, Dv);
        k_out2g<<<BB * 1024, 256, 0, stream>>>(bufY, bufZ, ow, ob, out);
    } else if (ws_size >= (NB + PLANE) * sizeof(float)) {
        // ---------- Path A: proven R7 pipeline.
        float* bufY = (float*)d_ws;
        float* bufU = bufY + NB;
        float* P    = out;
        for (int b = 0; b < BB; ++b) {
            k_inproj4<<<dim3(HW / 256, 2), 256, 0, stream>>>(
                x + (size_t)b * CIN * HW, ipw, ipb, bufU, bufU);
            k_conv<<<DI * 16, 256, 0, stream>>>(bufU, dww, dwb, bufY + (size_t)b * PLANE);
        }
        k_xproj<<<BB * (HW / 256), 256, 0, stream>>>(bufY, xpw, P);
        k_scan_w<<<BB * HH, 128, 0, stream>>>(bufY, P, A_log, dtw, dtb, Dv);
        k_scan_h<<<BB * 128, 256, 0, stream>>>(bufY, P, A_log, dtw, dtb, Dv);
        k_gate<<<BB * (HW / 256), 256, 0, stream>>>(bufY, x, wz, bz);
        k_out2<<<BB * (HW / 256), 256, 0, stream>>>(bufY, ow, ob, out);
    } else {
        // ---------- Path B: batch-sequential.
        float* bufA = (float*)d_ws;
        float* bufY = bufA + PLANE;
        for (int b = 0; b < BB; ++b) {
            const float* xb = x + (size_t)b * CIN * HW;
            k_inproj4<<<dim3(HW / 256, 2), 256, 0, stream>>>(xb, ipw, ipb, bufA, bufA);
            k_conv<<<DI * 16, 256, 0, stream>>>(bufA, dww, dwb, bufY);
            k_xproj<<<HW / 256, 256, 0, stream>>>(bufY, xpw, bufA);
            k_scan_w<<<HH, 128, 0, stream>>>(bufY, bufA, A_log, dtw, dtb, Dv);
            k_scan_h<<<128, 256, 0, stream>>>(bufY, bufA, A_log, dtw, dtb, Dv);
            k_gate<<<HW / 256, 256, 0, stream>>>(bufY, xb, wz, bz);
            k_out2<<<HW / 256, 256, 0, stream>>>(bufY, ow, ob, out + (size_t)b * CIN * HW);
        }
    }
}